// Round 10
// baseline (1600.400 us; speedup 1.0000x reference)
//
#include <hip/hip_runtime.h>

#define N_NODES 100000
#define NPAD    100096      // multiple of 128 for GEMM tiles
#define NE      1600000
#define DIM     128
#define ODIM    64
#define NORDER  4
#define NB      391         // buckets of 256 nodes (node >> 8)
#define PB_EDGES 16384      // edges per part_edges block
#define PB_BLKS  98         // ceil(NE / PB_EDGES)
#define GPB     25000       // propagate blocks per graph (4 nodes/block)

typedef _Float16 h8 __attribute__((ext_vector_type(8)));
typedef float f4 __attribute__((ext_vector_type(4)));
typedef unsigned u4v __attribute__((ext_vector_type(4)));
typedef unsigned u2v __attribute__((ext_vector_type(2)));

__device__ __forceinline__ float2 up2(unsigned p) {
    union { unsigned u; _Float16 h[2]; } c; c.u = p;
    return make_float2((float)c.h[0], (float)c.h[1]);
}
__device__ __forceinline__ unsigned pk2(float x, float y) {
    union { unsigned u; _Float16 h[2]; } c;
    c.h[0] = (_Float16)x; c.h[1] = (_Float16)y;
    return c.u;
}
__device__ __forceinline__ unsigned short f2hbits(float x) {
    union { _Float16 h; unsigned short s; } c;
    c.h = (_Float16)x;
    return c.s;
}
__device__ __forceinline__ float h2f(unsigned short s) {
    union { unsigned short u; _Float16 h; } c;
    c.u = s;
    return (float)c.h;
}
__device__ __forceinline__ void async_cp16(const void* g, void* l) {
    __builtin_amdgcn_global_load_lds((const __attribute__((address_space(1))) void*)g,
                                     (__attribute__((address_space(3))) void*)l, 16, 0, 0);
}

// ---------------------------------------------------------------------------
// CSR build — both graphs per kernel; no per-node global atomics;
// pairs packed to 4 B: (row << 8) | (col & 255).
// ---------------------------------------------------------------------------
__global__ __launch_bounds__(256) void hist_edges(const int* __restrict__ e0,
                                                  const int* __restrict__ e1,
                                                  int* __restrict__ bhist) {
    __shared__ int lh[NB];
    int t = threadIdx.x;
    int g = blockIdx.x >= 782;
    int blk = g ? (blockIdx.x - 782) : blockIdx.x;
    const int* colp = (g ? e1 : e0) + NE;
    int* bh = bhist + g * NB;
    for (int i = t; i < NB; i += 256) lh[i] = 0;
    __syncthreads();
    int base = blk * 2048 + t;
#pragma unroll
    for (int j = 0; j < 8; ++j) {
        int e = base + j * 256;
        if (e < NE) atomicAdd(&lh[colp[e] >> 8], 1);
    }
    __syncthreads();
    for (int i = t; i < NB; i += 256) if (lh[i]) atomicAdd(&bh[i], lh[i]);
}

// wave-parallel exclusive scan (wave = graph): boff (stride NB+1) + bcursor copy
__global__ void wave_scan(const int* __restrict__ in,
                          int* __restrict__ oexcl,
                          int* __restrict__ ocur,
                          int n) {
    int wv = threadIdx.x >> 6, lane = threadIdx.x & 63;
    if (wv >= 2) return;
    const int* I = in + wv * n;
    int* O = oexcl + wv * (n + 1);
    int* C = ocur + wv * n;
    int carry = 0;
    for (int base = 0; base < n; base += 64) {
        int i = base + lane;
        int v = (i < n) ? I[i] : 0;
        int s = v;
#pragma unroll
        for (int off = 1; off < 64; off <<= 1) {
            int x = __shfl_up(s, off, 64);
            if (lane >= off) s += x;
        }
        int excl = carry + s - v;
        if (i < n) {
            O[i] = excl;
            C[i] = excl;
        }
        carry += __shfl(s, 63, 64);
    }
    if (lane == 0) O[n] = carry;
}

// 16384 edges/block -> per-bucket chunks avg ~168 B (single-writer lines)
__global__ __launch_bounds__(1024) void part_edges(const int* __restrict__ e0,
                                                   const int* __restrict__ e1,
                                                   int* __restrict__ bcursor,
                                                   unsigned* __restrict__ pairs) {
    __shared__ int lh[NB];
    __shared__ int lpos[NB];
    int t = threadIdx.x;
    int g = blockIdx.x >= PB_BLKS;
    int blk = g ? (blockIdx.x - PB_BLKS) : blockIdx.x;
    const int* rowp = (g ? e1 : e0);
    const int* colp = rowp + NE;
    int* bc = bcursor + g * NB;
    unsigned* pr = pairs + (size_t)g * NE;
    for (int i = t; i < NB; i += 1024) lh[i] = 0;
    __syncthreads();
    int base = blk * PB_EDGES + t;
    int rank[16];
    short bk[16];
    unsigned char lcv[16];
#pragma unroll
    for (int j = 0; j < 16; ++j) {
        int e = base + j * 1024;
        rank[j] = -1;
        if (e < NE) {
            int c = colp[e];
            bk[j] = (short)(c >> 8);
            lcv[j] = (unsigned char)(c & 255);
            rank[j] = atomicAdd(&lh[c >> 8], 1);
        }
    }
    __syncthreads();
    for (int i = t; i < NB; i += 1024) {
        int n = lh[i];
        lpos[i] = n ? atomicAdd(&bc[i], n) : 0;
    }
    __syncthreads();
#pragma unroll
    for (int j = 0; j < 16; ++j) {
        int e = base + j * 1024;
        if (e < NE) {
            int b = bk[j];
            pr[lpos[b] + rank[j]] = ((unsigned)rowp[e] << 8) | lcv[j];
        }
    }
}

// per-bucket: degree count (LDS) -> block scan -> FINAL ptrv + dinv, scatter src
__global__ __launch_bounds__(256) void bucket_csr(const unsigned* __restrict__ pairs,
                                                  const int* __restrict__ boff,
                                                  int* __restrict__ ptrv,
                                                  float* __restrict__ dinv,
                                                  int* __restrict__ srcv) {
    __shared__ int lcnt[256];
    __shared__ int lbase[256];
    int t = threadIdx.x;
    int g = blockIdx.x >= NB;
    int b = g ? (blockIdx.x - NB) : blockIdx.x;
    const unsigned* pr = pairs + (size_t)g * NE;
    const int* bo = boff + g * (NB + 1);
    int* pv = ptrv + g * (N_NODES + 1);
    float* dv = dinv + g * N_NODES;
    int* sv = srcv + (size_t)g * NE;
    lcnt[t] = 0;
    __syncthreads();
    int s = bo[b], e = bo[b + 1];
    for (int i = s + t; i < e; i += 256)
        atomicAdd(&lcnt[pr[i] & 255u], 1);
    __syncthreads();
    int v = lcnt[t];
    lbase[t] = v;
    __syncthreads();
    for (int off = 1; off < 256; off <<= 1) {
        int x = (t >= off) ? lbase[t - off] : 0;
        __syncthreads();
        lbase[t] += x;
        __syncthreads();
    }
    int node = (b << 8) + t;
    int gbase = s + lbase[t] - v;
    lbase[t] = gbase;
    lcnt[t] = 0;
    if (node < N_NODES) {
        pv[node] = gbase;
        dv[node] = rsqrtf((float)(v + 1));
    }
    if (b == 0 && g == 0 && t == 0) ptrv[N_NODES] = NE;
    if (b == 0 && g == 1 && t == 0) ptrv[2 * N_NODES + 1] = NE;
    __syncthreads();
    for (int i = s + t; i < e; i += 256) {
        unsigned pk = pr[i];
        int lc = (int)(pk & 255u);
        int pos = lbase[lc] + atomicAdd(&lcnt[lc], 1);
        sv[pos] = (int)(pk >> 8);
    }
}

// ---------------------------------------------------------------------------
// casts
// ---------------------------------------------------------------------------
// S0 slices + zero pad rows of S0 AND both Tbig buffers (replaces memset).
__global__ __launch_bounds__(256) void s0cast(const float* __restrict__ x,
                                              const float* __restrict__ dinv,
                                              unsigned* __restrict__ S0o,
                                              unsigned* __restrict__ S0a,
                                              unsigned* __restrict__ To,
                                              unsigned* __restrict__ Ta) {
    int idx = blockIdx.x * 256 + threadIdx.x;
    if (idx >= NPAD * 64) return;
    int m = idx >> 6, u = idx & 63;
    if (m < N_NODES) {
        int e = (m << 7) + u * 2;
        float a = x[e], b = x[e + 1];
        float d0 = dinv[m];
        float d1 = dinv[N_NODES + m];
        S0o[idx] = pk2(d0 * a, d0 * b);
        S0a[idx] = pk2(d1 * a, d1 * b);
    } else {
        S0o[idx] = 0u;
        S0a[idx] = 0u;
        u4v z = (u4v)(0u);
        *(u4v*)&To[(size_t)m * 256 + u * 4] = z;
        *(u4v*)&Ta[(size_t)m * 256 + u * 4] = z;
    }
}

// Wt[g][i][k8][n][k7] = (half) W_g[i][k8*8+k7][n]; tail: clfWt[n][k]=clfW[k][n].
// Fills params [0]=sw0 [1]=sw1 [2..129]=bias-sum b0 [130..257]=b1; zeroes bhist.
__global__ __launch_bounds__(256) void wcast(const float* __restrict__ Wo,
                                             const float* __restrict__ Wa,
                                             const float* __restrict__ cw,
                                             const float* __restrict__ bO,
                                             const float* __restrict__ bA,
                                             const float* __restrict__ fw,
                                             unsigned short* __restrict__ Wt,
                                             float* __restrict__ params,
                                             int* __restrict__ bhist) {
    int idx = blockIdx.x * 256 + threadIdx.x;
    if (idx >= 2 * 5 * DIM * DIM + ODIM * DIM) return;
    if (idx < 2 * NB) bhist[idx] = 0;
    if (idx < 258) {
        if (idx < 2) {
            float f0 = fw[0], f1 = fw[1];
            float mx = fmaxf(f0, f1);
            float e0 = expf(f0 - mx), e1 = expf(f1 - mx);
            params[idx] = (idx == 0 ? e0 : e1) / (e0 + e1);
        } else if (idx < 130) {
            int n = idx - 2;
            float s = 0.f;
            for (int i = 0; i <= NORDER; ++i) s += bO[i * DIM + n];
            params[idx] = s;
        } else {
            int n = idx - 130;
            float s = 0.f;
            for (int i = 0; i <= NORDER; ++i) s += bA[i * DIM + n];
            params[idx] = s;
        }
    }
    if (idx < 2 * 5 * DIM * DIM) {
        int g   = idx / (5 * DIM * DIM);
        int rem = idx % (5 * DIM * DIM);
        int i   = rem / (DIM * DIM);
        int r2  = rem % (DIM * DIM);
        int k8  = r2 >> 10;
        int n   = (r2 >> 3) & 127;
        int k7  = r2 & 7;
        int k   = k8 * 8 + k7;
        const float* W = g ? Wa : Wo;
        Wt[idx] = f2hbits(W[(i * DIM + k) * DIM + n]);
    } else {
        int j = idx - 2 * 5 * DIM * DIM;
        int n = j >> 7, k = j & 127;
        Wt[idx] = f2hbits(cw[k * ODIM + n]);
    }
}

// ---------------------------------------------------------------------------
// Propagation, S-form: Sout[v] = dinv[v]^2 * (sum_u Sin[u] + Sin[v]).
// PAIR-GATHER (round-9 semantics, verified correct): one dwordx2 instruction
// fetches TWO 256-B rows (lanes 0-31 -> row u[2j], lanes 32-63 -> u[2j+1];
// 8 B/lane). __shfl_xor(32) cross-half reduce; half-wave dwordx2 store.
// ROUND-9 BUG FIX: __launch_bounds__(256,8) capped VGPRs at 64 -> compiler
// spilled tw/gq/u arrays to LDS (LDS_Block_Size=16384, 6.9e7 bank-conflict
// cycles, 2.75x regression). (256,4) gives the 128-VGPR budget the ~62-reg
// live set needs; arrays stay in registers. 16 waves/CU (was ~17) - fine.
// vmem insts per 16-edge chunk: ~4-16 srcv + 8 gathers (was 16+16).
// ---------------------------------------------------------------------------
template<int SIN>
__global__ __launch_bounds__(256, 4) void propagate2(const unsigned* __restrict__ T0i,
                                                     unsigned* __restrict__ T0o,
                                                     const unsigned* __restrict__ T1i,
                                                     unsigned* __restrict__ T1o,
                                                     const int* __restrict__ ptrv,
                                                     const int* __restrict__ srcv,
                                                     const float* __restrict__ dinv) {
    int bid = blockIdx.x;
    int g = bid >= GPB;
    bid -= g * GPB;
    const unsigned* Tin = g ? T1i : T0i;
    unsigned* Tout      = g ? T1o : T0o;
    const int* pv   = ptrv + g * (N_NODES + 1);
    const int* sv   = srcv + (size_t)g * NE;
    const float* dp = dinv + g * N_NODES;
    int gid  = bid * 256 + threadIdx.x;
    int lane = threadIdx.x & 63;
    int half = lane >> 5;
    int l31  = lane & 31;
    int v    = __builtin_amdgcn_readfirstlane(gid >> 6);
    if (v >= N_NODES) return;
    float dv = dp[v];

    // self row in half 0; half 1 reads the zero dummy row (L1-hot)
    int uuS = half ? N_NODES : v;
    u2v sw = *(const u2v*)&Tin[(size_t)(unsigned)uuS * SIN + l31 * 2];
    float2 p0 = up2(sw.x), p1 = up2(sw.y);
    float a0 = p0.x, a1 = p0.y, a2 = p1.x, a3 = p1.y;

    int beg = pv[v], end = pv[v + 1];
    for (int k = beg; k < end; k += 16) {
        int4 gq[4];
#pragma unroll
        for (int i = 0; i < 4; ++i)
            __builtin_memcpy(&gq[i], &sv[k + 4 * i], 16);   // broadcast chunk
        int u[16];
#pragma unroll
        for (int i = 0; i < 4; ++i) {
            u[4 * i + 0] = gq[i].x; u[4 * i + 1] = gq[i].y;
            u[4 * i + 2] = gq[i].z; u[4 * i + 3] = gq[i].w;
        }
        if (k + 16 > end) {                                 // tail: mask to dummy
#pragma unroll
            for (int j = 0; j < 16; ++j)
                if (k + j >= end) u[j] = N_NODES;
        }
        __builtin_amdgcn_sched_barrier(0);
        u2v tw[8];
#pragma unroll
        for (int j = 0; j < 8; ++j) {
            int uu = half ? u[2 * j + 1] : u[2 * j];
            tw[j] = *(const u2v*)&Tin[(size_t)((unsigned)uu * SIN) + l31 * 2];
        }
        __builtin_amdgcn_sched_barrier(0);
#pragma unroll
        for (int j = 0; j < 8; ++j) {
            float2 q0 = up2(tw[j].x), q1 = up2(tw[j].y);
            a0 += q0.x; a1 += q0.y; a2 += q1.x; a3 += q1.y;
        }
    }
    // cross-half reduce: total over even-edge half + odd-edge half
    a0 += __shfl_xor(a0, 32);
    a1 += __shfl_xor(a1, 32);
    a2 += __shfl_xor(a2, 32);
    a3 += __shfl_xor(a3, 32);
    if (half == 0) {
        float s2 = dv * dv;
        u2v o;
        o.x = pk2(s2 * a0, s2 * a1);
        o.y = pk2(s2 * a2, s2 * a3);
        *(u2v*)&Tout[(size_t)v * 256 + l31 * 2] = o;
    }
}

// ---------------------------------------------------------------------------
// Branch-0 GEMM (round-2 proven structure: single 32KB LDS stage, 2 barriers
// per K-slice). H0[m][n] = fp16( sw0 * relu( acc[m][n]/dinv[m] + bs0[n] ) )
// ---------------------------------------------------------------------------
__global__ __launch_bounds__(256, 3) void gemmH0(
        const unsigned short* __restrict__ A0,
        const unsigned short* __restrict__ A,
        const unsigned short* __restrict__ Wt,
        const float* __restrict__ params,
        const float* __restrict__ dinv,
        unsigned short* __restrict__ H0) {
    __shared__ unsigned short Bl[DIM * DIM];   // 32 KB
    int t = threadIdx.x;
    int lane = t & 63, wv = t >> 6;
    int m0 = blockIdx.x * 128 + wv * 32;
    int l15 = lane & 15, q = lane >> 4;
    float sw0 = params[0];
    float bs[8];
#pragma unroll
    for (int nt = 0; nt < 8; ++nt) bs[nt] = params[2 + nt * 16 + l15];

    f4 acc[2][8];
#pragma unroll
    for (int mt = 0; mt < 2; ++mt)
#pragma unroll
        for (int nt = 0; nt < 8; ++nt) acc[mt][nt] = (f4)(0.f);

#pragma unroll
    for (int i = 0; i < 5; ++i) {
        const unsigned short* WtI = Wt + (size_t)i * DIM * DIM;
        const unsigned short* Ai = (i == 0) ? A0 : (A + (size_t)(i - 1) * DIM);
        const int rs = (i == 0) ? DIM : 512;
        h8 af[2][4];
#pragma unroll
        for (int mt = 0; mt < 2; ++mt)
#pragma unroll
            for (int kc = 0; kc < 4; ++kc)
                af[mt][kc] = *(const h8*)(Ai + (size_t)(m0 + mt * 16 + l15) * rs
                                             + (kc * 4 + q) * 8);
#pragma unroll
        for (int c = 0; c < 8; ++c) {
            int ci = c * 4 + wv;
            async_cp16(WtI + ci * 512 + lane * 8, &Bl[ci * 512]);
        }
        __syncthreads();
#pragma unroll
        for (int kc = 0; kc < 4; ++kc) {
            int c = kc * 4 + q;
#pragma unroll
            for (int nt = 0; nt < 8; ++nt) {
                h8 bf = *(const h8*)&Bl[(size_t)(c * 128 + nt * 16 + l15) * 8];
                acc[0][nt] = __builtin_amdgcn_mfma_f32_16x16x32_f16(af[0][kc], bf, acc[0][nt], 0, 0, 0);
                acc[1][nt] = __builtin_amdgcn_mfma_f32_16x16x32_f16(af[1][kc], bf, acc[1][nt], 0, 0, 0);
            }
        }
        __syncthreads();
    }
#pragma unroll
    for (int mt = 0; mt < 2; ++mt) {
        float rd[4];
#pragma unroll
        for (int r = 0; r < 4; ++r) {
            int row = m0 + mt * 16 + q * 4 + r;
            rd[r] = 1.0f / dinv[row < N_NODES ? row : (N_NODES - 1)];
        }
#pragma unroll
        for (int nt = 0; nt < 8; ++nt) {
#pragma unroll
            for (int r = 0; r < 4; ++r) {
                int row = m0 + mt * 16 + q * 4 + r;
                H0[(size_t)row * DIM + nt * 16 + l15] =
                    f2hbits(sw0 * fmaxf(rd[r] * acc[mt][nt][r] + bs[nt], 0.f));
            }
        }
    }
}

// ---------------------------------------------------------------------------
// Branch-1 GEMM + fusion + classifier (round-2 proven; Hl aliases staging).
// ---------------------------------------------------------------------------
__global__ __launch_bounds__(256, 2) void gemm_fused2(
        const unsigned short* __restrict__ A0,
        const unsigned short* __restrict__ A,
        const unsigned short* __restrict__ Wt,
        const unsigned short* __restrict__ H0,
        const float* __restrict__ params,
        const float* __restrict__ dinv,
        const unsigned short* __restrict__ clfWt,
        const float* __restrict__ clfB,
        float* __restrict__ out) {
    __shared__ unsigned short BlH[DIM * 132];   // 33.8 KB
    unsigned short* Bl = BlH;
    unsigned short* Hl = BlH;
    int t = threadIdx.x;
    int lane = t & 63, wv = t >> 6;
    int m0 = blockIdx.x * 128 + wv * 32;
    int l15 = lane & 15, q = lane >> 4;
    float sw1 = params[1];
    float bs[8];
#pragma unroll
    for (int nt = 0; nt < 8; ++nt) bs[nt] = params[130 + nt * 16 + l15];

    f4 acc[2][8];
#pragma unroll
    for (int mt = 0; mt < 2; ++mt)
#pragma unroll
        for (int nt = 0; nt < 8; ++nt) acc[mt][nt] = (f4)(0.f);

#pragma unroll
    for (int i = 0; i < 5; ++i) {
        const unsigned short* WtI = Wt + (size_t)i * DIM * DIM;
        const unsigned short* Ai = (i == 0) ? A0 : (A + (size_t)(i - 1) * DIM);
        const int rs = (i == 0) ? DIM : 512;
        h8 af[2][4];
#pragma unroll
        for (int mt = 0; mt < 2; ++mt)
#pragma unroll
            for (int kc = 0; kc < 4; ++kc)
                af[mt][kc] = *(const h8*)(Ai + (size_t)(m0 + mt * 16 + l15) * rs
                                             + (kc * 4 + q) * 8);
#pragma unroll
        for (int c = 0; c < 8; ++c) {
            int ci = c * 4 + wv;
            async_cp16(WtI + ci * 512 + lane * 8, &Bl[ci * 512]);
        }
        __syncthreads();
#pragma unroll
        for (int kc = 0; kc < 4; ++kc) {
            int c = kc * 4 + q;
#pragma unroll
            for (int nt = 0; nt < 8; ++nt) {
                h8 bf = *(const h8*)&Bl[(size_t)(c * 128 + nt * 16 + l15) * 8];
                acc[0][nt] = __builtin_amdgcn_mfma_f32_16x16x32_f16(af[0][kc], bf, acc[0][nt], 0, 0, 0);
                acc[1][nt] = __builtin_amdgcn_mfma_f32_16x16x32_f16(af[1][kc], bf, acc[1][nt], 0, 0, 0);
            }
        }
        __syncthreads();
    }

    // fuse with H0 (global read, 0 bank conflicts) into LDS Hl
#pragma unroll
    for (int mt = 0; mt < 2; ++mt) {
        float rd[4];
#pragma unroll
        for (int r = 0; r < 4; ++r) {
            int row = m0 + mt * 16 + q * 4 + r;
            rd[r] = 1.0f / dinv[row < N_NODES ? row : (N_NODES - 1)];
        }
#pragma unroll
        for (int nt = 0; nt < 8; ++nt) {
            int col = nt * 16 + l15;
#pragma unroll
            for (int r = 0; r < 4; ++r) {
                int lrow = wv * 32 + mt * 16 + q * 4 + r;
                int grow = m0 + mt * 16 + q * 4 + r;
                float h = sw1 * fmaxf(rd[r] * acc[mt][nt][r] + bs[nt], 0.f)
                        + h2f(H0[(size_t)grow * DIM + col]);
                Hl[lrow * 132 + col] = f2hbits(h);
            }
        }
    }
    __syncthreads();

    f4 o[2][4];
#pragma unroll
    for (int mt = 0; mt < 2; ++mt)
#pragma unroll
        for (int n2 = 0; n2 < 4; ++n2) o[mt][n2] = (f4)(0.f);
#pragma unroll
    for (int kc = 0; kc < 4; ++kc) {
        int c = kc * 4 + q;
        h8 ha[2];
#pragma unroll
        for (int mt = 0; mt < 2; ++mt)
            ha[mt] = *(const h8*)&Hl[(wv * 32 + mt * 16 + l15) * 132 + c * 8];
#pragma unroll
        for (int n2 = 0; n2 < 4; ++n2) {
            h8 bf = *(const h8*)&clfWt[(size_t)(n2 * 16 + l15) * DIM + c * 8];
            o[0][n2] = __builtin_amdgcn_mfma_f32_16x16x32_f16(ha[0], bf, o[0][n2], 0, 0, 0);
            o[1][n2] = __builtin_amdgcn_mfma_f32_16x16x32_f16(ha[1], bf, o[1][n2], 0, 0, 0);
        }
    }
#pragma unroll
    for (int mt = 0; mt < 2; ++mt)
#pragma unroll
        for (int n2 = 0; n2 < 4; ++n2) {
            int col = n2 * 16 + l15;
            float cbv = clfB[col];
#pragma unroll
            for (int r = 0; r < 4; ++r) {
                int row = m0 + mt * 16 + q * 4 + r;
                if (row < N_NODES) out[(size_t)row * ODIM + col] = o[mt][n2][r] + cbv;
            }
        }
}

// ---------------------------------------------------------------------------
extern "C" void kernel_launch(void* const* d_in, const int* in_sizes, int n_in,
                              void* d_out, int out_size, void* d_ws, size_t ws_size,
                              hipStream_t stream) {
    const float* x   = (const float*)d_in[0];
    const int*   ei  = (const int*)d_in[1];
    const int*   gi  = (const int*)d_in[2];
    const float* w_o = (const float*)d_in[3];
    const float* b_o = (const float*)d_in[4];
    const float* w_a = (const float*)d_in[5];
    const float* b_a = (const float*)d_in[6];
    const float* fw  = (const float*)d_in[7];
    const float* cw  = (const float*)d_in[8];
    const float* cb  = (const float*)d_in[9];
    float* out = (float*)d_out;

    auto align256 = [](size_t b) { return (b + 255) & ~(size_t)255; };
    const size_t szTbig = (size_t)NPAD * 256 * 4;            // 102.5 MB
    const size_t szS0   = (size_t)NPAD * 64 * 4;             // 25.6 MB
    const size_t szH0   = (size_t)NPAD * DIM * 2;            // 25.6 MB
    const size_t szWt   = ((size_t)2 * 5 * DIM * DIM + ODIM * DIM) * 2;
    const size_t szPar  = 258 * 4;
    const size_t szDinv = (size_t)2 * N_NODES * 4;
    const size_t szPairs= (size_t)2 * NE * 4;                // 12.8 MB
    const size_t szSrc  = ((size_t)2 * NE + 16) * 4;         // +16-int slack for x4 reads
    const size_t szPtr  = (size_t)2 * (N_NODES + 1) * 4;
    const size_t szBh   = (size_t)2 * NB * 4;
    const size_t szBo   = (size_t)2 * (NB + 1) * 4;

    // merged layout: 2x Tbig, pairs aliased into Tbig_a (dead before 1st write)
    const size_t needBig = align256(szTbig) * 2 + align256(szS0) * 2 + align256(szH0)
                         + align256(szWt) + align256(szPar) + align256(szDinv)
                         + align256(szSrc) + align256(szPtr) + align256(szBh) * 2
                         + align256(szBo);
    const bool big = (ws_size >= needBig);

    char* p = (char*)d_ws;
    auto alloc = [&](size_t bytes) {
        void* r = (void*)p;
        p += (bytes + 255) & ~(size_t)255;
        return r;
    };
    unsigned* Tbig_o = (unsigned*)alloc(szTbig);
    unsigned* Tbig_a = big ? (unsigned*)alloc(szTbig) : Tbig_o;
    unsigned* pairs  = big ? Tbig_a : (unsigned*)alloc(szPairs);
    unsigned* S0o  = (unsigned*)alloc(szS0);
    unsigned* S0a  = (unsigned*)alloc(szS0);
    unsigned short* H0 = (unsigned short*)alloc(szH0);
    unsigned short* Wt = (unsigned short*)alloc(szWt);
    float* params = (float*)alloc(szPar);
    float* dinv  = (float*)alloc(szDinv);
    int* csr_src = (int*)alloc(szSrc);
    int* csr_ptr = (int*)alloc(szPtr);
    int* bhist   = (int*)alloc(szBh);
    int* boff    = (int*)alloc(szBo);
    int* bcursor = (int*)alloc(szBh);

    const int gX  = (NPAD * 64 + 255) / 256;        // 25024
    const int gW  = (2 * 5 * DIM * DIM + ODIM * DIM + 255) / 256;
    const int gM  = NPAD / 128;                     // 782

    // wcast also zeroes bhist (first dispatch on the stream)
    wcast<<<gW, 256, 0, stream>>>(w_o, w_a, cw, b_o, b_a, fw, Wt, params, bhist);

    // ---- CSR build for BOTH graphs ----
    hist_edges<<<2 * 782, 256, 0, stream>>>(ei, gi, bhist);
    wave_scan<<<1, 128, 0, stream>>>(bhist, boff, bcursor, NB);
    part_edges<<<2 * PB_BLKS, 1024, 0, stream>>>(ei, gi, bcursor, pairs);
    bucket_csr<<<2 * NB, 256, 0, stream>>>(pairs, boff, csr_ptr, dinv, csr_src);

    // ---- S0 slices + Tbig pad-row zeroing ----
    s0cast<<<gX, 256, 0, stream>>>(x, dinv, S0o, S0a, Tbig_o, Tbig_a);

    if (big) {
        // ---- both branches propagate in one dispatch per order ----
        propagate2<64><<<2 * GPB, 256, 0, stream>>>(S0o, Tbig_o, S0a, Tbig_a,
                                                    csr_ptr, csr_src, dinv);
        propagate2<256><<<2 * GPB, 256, 0, stream>>>(Tbig_o, Tbig_o + 64,
                                                     Tbig_a, Tbig_a + 64,
                                                     csr_ptr, csr_src, dinv);
        propagate2<256><<<2 * GPB, 256, 0, stream>>>(Tbig_o + 64, Tbig_o + 128,
                                                     Tbig_a + 64, Tbig_a + 128,
                                                     csr_ptr, csr_src, dinv);
        propagate2<256><<<2 * GPB, 256, 0, stream>>>(Tbig_o + 128, Tbig_o + 192,
                                                     Tbig_a + 128, Tbig_a + 192,
                                                     csr_ptr, csr_src, dinv);
        gemmH0<<<gM, 256, 0, stream>>>((const unsigned short*)S0o,
                                       (const unsigned short*)Tbig_o,
                                       Wt, params, dinv, H0);
        gemm_fused2<<<gM, 256, 0, stream>>>((const unsigned short*)S0a,
                                            (const unsigned short*)Tbig_a,
                                            Wt + (size_t)5 * DIM * DIM,
                                            H0, params, dinv + N_NODES,
                                            Wt + (size_t)2 * 5 * DIM * DIM, cb, out);
    } else {
        // ---- fallback: sequential branches sharing one Tbig ----
        propagate2<64><<<GPB, 256, 0, stream>>>(S0o, Tbig_o, S0o, Tbig_o,
                                                csr_ptr, csr_src, dinv);
        propagate2<256><<<GPB, 256, 0, stream>>>(Tbig_o, Tbig_o + 64, Tbig_o, Tbig_o + 64,
                                                 csr_ptr, csr_src, dinv);
        propagate2<256><<<GPB, 256, 0, stream>>>(Tbig_o + 64, Tbig_o + 128,
                                                 Tbig_o + 64, Tbig_o + 128,
                                                 csr_ptr, csr_src, dinv);
        propagate2<256><<<GPB, 256, 0, stream>>>(Tbig_o + 128, Tbig_o + 192,
                                                 Tbig_o + 128, Tbig_o + 192,
                                                 csr_ptr, csr_src, dinv);
        gemmH0<<<gM, 256, 0, stream>>>((const unsigned short*)S0o,
                                       (const unsigned short*)Tbig_o,
                                       Wt, params, dinv, H0);
        const int* pv = csr_ptr + (N_NODES + 1);
        const int* sv = csr_src + (size_t)NE;
        const float* dv = dinv + (size_t)N_NODES;
        propagate2<64><<<GPB, 256, 0, stream>>>(S0a, Tbig_o, S0a, Tbig_o, pv, sv, dv);
        propagate2<256><<<GPB, 256, 0, stream>>>(Tbig_o, Tbig_o + 64, Tbig_o, Tbig_o + 64,
                                                 pv, sv, dv);
        propagate2<256><<<GPB, 256, 0, stream>>>(Tbig_o + 64, Tbig_o + 128,
                                                 Tbig_o + 64, Tbig_o + 128, pv, sv, dv);
        propagate2<256><<<GPB, 256, 0, stream>>>(Tbig_o + 128, Tbig_o + 192,
                                                 Tbig_o + 128, Tbig_o + 192, pv, sv, dv);
        gemm_fused2<<<gM, 256, 0, stream>>>((const unsigned short*)S0a,
                                            (const unsigned short*)Tbig_o,
                                            Wt + (size_t)5 * DIM * DIM,
                                            H0, params, dinv + N_NODES,
                                            Wt + (size_t)2 * 5 * DIM * DIM, cb, out);
    }
}

// Round 12
// 773.037 us; speedup vs baseline: 2.0703x; 2.0703x over previous
//
#include <hip/hip_runtime.h>

#define N_NODES 100000
#define NPAD    100096      // multiple of 128 for GEMM tiles
#define NE      1600000
#define DIM     128
#define ODIM    64
#define NORDER  4
#define NB      391         // buckets of 256 nodes (node >> 8)
#define PB_EDGES 16384      // edges per part_edges block
#define PB_BLKS  98         // ceil(NE / PB_EDGES)
#define GPB     25000       // propagate blocks per graph (4 nodes/block)

typedef _Float16 h8 __attribute__((ext_vector_type(8)));
typedef float f4 __attribute__((ext_vector_type(4)));
typedef unsigned u4v __attribute__((ext_vector_type(4)));
typedef unsigned u2v __attribute__((ext_vector_type(2)));

__device__ __forceinline__ float2 up2(unsigned p) {
    union { unsigned u; _Float16 h[2]; } c; c.u = p;
    return make_float2((float)c.h[0], (float)c.h[1]);
}
__device__ __forceinline__ unsigned pk2(float x, float y) {
    union { unsigned u; _Float16 h[2]; } c;
    c.h[0] = (_Float16)x; c.h[1] = (_Float16)y;
    return c.u;
}
__device__ __forceinline__ unsigned short f2hbits(float x) {
    union { _Float16 h; unsigned short s; } c;
    c.h = (_Float16)x;
    return c.s;
}
__device__ __forceinline__ float h2f(unsigned short s) {
    union { unsigned short u; _Float16 h; } c;
    c.u = s;
    return (float)c.h;
}
__device__ __forceinline__ void async_cp16(const void* g, void* l) {
    __builtin_amdgcn_global_load_lds((const __attribute__((address_space(1))) void*)g,
                                     (__attribute__((address_space(3))) void*)l, 16, 0, 0);
}

// ---------------------------------------------------------------------------
// CSR build — both graphs per kernel; no per-node global atomics;
// pairs packed to 4 B: (row << 8) | (col & 255).
// ---------------------------------------------------------------------------
__global__ __launch_bounds__(256) void hist_edges(const int* __restrict__ e0,
                                                  const int* __restrict__ e1,
                                                  int* __restrict__ bhist) {
    __shared__ int lh[NB];
    int t = threadIdx.x;
    int g = blockIdx.x >= 782;
    int blk = g ? (blockIdx.x - 782) : blockIdx.x;
    const int* colp = (g ? e1 : e0) + NE;
    int* bh = bhist + g * NB;
    for (int i = t; i < NB; i += 256) lh[i] = 0;
    __syncthreads();
    int base = blk * 2048 + t;
#pragma unroll
    for (int j = 0; j < 8; ++j) {
        int e = base + j * 256;
        if (e < NE) atomicAdd(&lh[colp[e] >> 8], 1);
    }
    __syncthreads();
    for (int i = t; i < NB; i += 256) if (lh[i]) atomicAdd(&bh[i], lh[i]);
}

// wave-parallel exclusive scan (wave = graph): boff (stride NB+1) + bcursor copy
__global__ void wave_scan(const int* __restrict__ in,
                          int* __restrict__ oexcl,
                          int* __restrict__ ocur,
                          int n) {
    int wv = threadIdx.x >> 6, lane = threadIdx.x & 63;
    if (wv >= 2) return;
    const int* I = in + wv * n;
    int* O = oexcl + wv * (n + 1);
    int* C = ocur + wv * n;
    int carry = 0;
    for (int base = 0; base < n; base += 64) {
        int i = base + lane;
        int v = (i < n) ? I[i] : 0;
        int s = v;
#pragma unroll
        for (int off = 1; off < 64; off <<= 1) {
            int x = __shfl_up(s, off, 64);
            if (lane >= off) s += x;
        }
        int excl = carry + s - v;
        if (i < n) {
            O[i] = excl;
            C[i] = excl;
        }
        carry += __shfl(s, 63, 64);
    }
    if (lane == 0) O[n] = carry;
}

// 16384 edges/block -> per-bucket chunks avg ~168 B (single-writer lines)
__global__ __launch_bounds__(1024) void part_edges(const int* __restrict__ e0,
                                                   const int* __restrict__ e1,
                                                   int* __restrict__ bcursor,
                                                   unsigned* __restrict__ pairs) {
    __shared__ int lh[NB];
    __shared__ int lpos[NB];
    int t = threadIdx.x;
    int g = blockIdx.x >= PB_BLKS;
    int blk = g ? (blockIdx.x - PB_BLKS) : blockIdx.x;
    const int* rowp = (g ? e1 : e0);
    const int* colp = rowp + NE;
    int* bc = bcursor + g * NB;
    unsigned* pr = pairs + (size_t)g * NE;
    for (int i = t; i < NB; i += 1024) lh[i] = 0;
    __syncthreads();
    int base = blk * PB_EDGES + t;
    int rank[16];
    short bk[16];
    unsigned char lcv[16];
#pragma unroll
    for (int j = 0; j < 16; ++j) {
        int e = base + j * 1024;
        rank[j] = -1;
        if (e < NE) {
            int c = colp[e];
            bk[j] = (short)(c >> 8);
            lcv[j] = (unsigned char)(c & 255);
            rank[j] = atomicAdd(&lh[c >> 8], 1);
        }
    }
    __syncthreads();
    for (int i = t; i < NB; i += 1024) {
        int n = lh[i];
        lpos[i] = n ? atomicAdd(&bc[i], n) : 0;
    }
    __syncthreads();
#pragma unroll
    for (int j = 0; j < 16; ++j) {
        int e = base + j * 1024;
        if (e < NE) {
            int b = bk[j];
            pr[lpos[b] + rank[j]] = ((unsigned)rowp[e] << 8) | lcv[j];
        }
    }
}

// per-bucket: degree count (LDS) -> block scan -> FINAL ptrv + dinv, scatter src
__global__ __launch_bounds__(256) void bucket_csr(const unsigned* __restrict__ pairs,
                                                  const int* __restrict__ boff,
                                                  int* __restrict__ ptrv,
                                                  float* __restrict__ dinv,
                                                  int* __restrict__ srcv) {
    __shared__ int lcnt[256];
    __shared__ int lbase[256];
    int t = threadIdx.x;
    int g = blockIdx.x >= NB;
    int b = g ? (blockIdx.x - NB) : blockIdx.x;
    const unsigned* pr = pairs + (size_t)g * NE;
    const int* bo = boff + g * (NB + 1);
    int* pv = ptrv + g * (N_NODES + 1);
    float* dv = dinv + g * N_NODES;
    int* sv = srcv + (size_t)g * NE;
    lcnt[t] = 0;
    __syncthreads();
    int s = bo[b], e = bo[b + 1];
    for (int i = s + t; i < e; i += 256)
        atomicAdd(&lcnt[pr[i] & 255u], 1);
    __syncthreads();
    int v = lcnt[t];
    lbase[t] = v;
    __syncthreads();
    for (int off = 1; off < 256; off <<= 1) {
        int x = (t >= off) ? lbase[t - off] : 0;
        __syncthreads();
        lbase[t] += x;
        __syncthreads();
    }
    int node = (b << 8) + t;
    int gbase = s + lbase[t] - v;
    lbase[t] = gbase;
    lcnt[t] = 0;
    if (node < N_NODES) {
        pv[node] = gbase;
        dv[node] = rsqrtf((float)(v + 1));
    }
    if (b == 0 && g == 0 && t == 0) ptrv[N_NODES] = NE;
    if (b == 0 && g == 1 && t == 0) ptrv[2 * N_NODES + 1] = NE;
    __syncthreads();
    for (int i = s + t; i < e; i += 256) {
        unsigned pk = pr[i];
        int lc = (int)(pk & 255u);
        int pos = lbase[lc] + atomicAdd(&lcnt[lc], 1);
        sv[pos] = (int)(pk >> 8);
    }
}

// ---------------------------------------------------------------------------
// casts
// ---------------------------------------------------------------------------
// S0 slices + zero pad rows of S0 AND both Tbig buffers (replaces memset).
__global__ __launch_bounds__(256) void s0cast(const float* __restrict__ x,
                                              const float* __restrict__ dinv,
                                              unsigned* __restrict__ S0o,
                                              unsigned* __restrict__ S0a,
                                              unsigned* __restrict__ To,
                                              unsigned* __restrict__ Ta) {
    int idx = blockIdx.x * 256 + threadIdx.x;
    if (idx >= NPAD * 64) return;
    int m = idx >> 6, u = idx & 63;
    if (m < N_NODES) {
        int e = (m << 7) + u * 2;
        float a = x[e], b = x[e + 1];
        float d0 = dinv[m];
        float d1 = dinv[N_NODES + m];
        S0o[idx] = pk2(d0 * a, d0 * b);
        S0a[idx] = pk2(d1 * a, d1 * b);
    } else {
        S0o[idx] = 0u;
        S0a[idx] = 0u;
        u4v z = (u4v)(0u);
        *(u4v*)&To[(size_t)m * 256 + u * 4] = z;
        *(u4v*)&Ta[(size_t)m * 256 + u * 4] = z;
    }
}

// Wt[g][i][k8][n][k7] = (half) W_g[i][k8*8+k7][n]; tail: clfWt[n][k]=clfW[k][n].
// Fills params [0]=sw0 [1]=sw1 [2..129]=bias-sum b0 [130..257]=b1; zeroes bhist.
__global__ __launch_bounds__(256) void wcast(const float* __restrict__ Wo,
                                             const float* __restrict__ Wa,
                                             const float* __restrict__ cw,
                                             const float* __restrict__ bO,
                                             const float* __restrict__ bA,
                                             const float* __restrict__ fw,
                                             unsigned short* __restrict__ Wt,
                                             float* __restrict__ params,
                                             int* __restrict__ bhist) {
    int idx = blockIdx.x * 256 + threadIdx.x;
    if (idx >= 2 * 5 * DIM * DIM + ODIM * DIM) return;
    if (idx < 2 * NB) bhist[idx] = 0;
    if (idx < 258) {
        if (idx < 2) {
            float f0 = fw[0], f1 = fw[1];
            float mx = fmaxf(f0, f1);
            float e0 = expf(f0 - mx), e1 = expf(f1 - mx);
            params[idx] = (idx == 0 ? e0 : e1) / (e0 + e1);
        } else if (idx < 130) {
            int n = idx - 2;
            float s = 0.f;
            for (int i = 0; i <= NORDER; ++i) s += bO[i * DIM + n];
            params[idx] = s;
        } else {
            int n = idx - 130;
            float s = 0.f;
            for (int i = 0; i <= NORDER; ++i) s += bA[i * DIM + n];
            params[idx] = s;
        }
    }
    if (idx < 2 * 5 * DIM * DIM) {
        int g   = idx / (5 * DIM * DIM);
        int rem = idx % (5 * DIM * DIM);
        int i   = rem / (DIM * DIM);
        int r2  = rem % (DIM * DIM);
        int k8  = r2 >> 10;
        int n   = (r2 >> 3) & 127;
        int k7  = r2 & 7;
        int k   = k8 * 8 + k7;
        const float* W = g ? Wa : Wo;
        Wt[idx] = f2hbits(W[(i * DIM + k) * DIM + n]);
    } else {
        int j = idx - 2 * 5 * DIM * DIM;
        int n = j >> 7, k = j & 127;
        Wt[idx] = f2hbits(cw[k * ODIM + n]);
    }
}

// ---------------------------------------------------------------------------
// Propagation, S-form: Sout[v] = dinv[v]^2 * (sum_u Sin[u] + Sin[v]).
// PAIR-GATHER, ARRAY-FREE. Round-9/10 lesson: local arrays touched by
// memcpy/address-of become allocas -> amdgpu-promote-alloca puts them in
// LDS (LDS_Block_Size=16384, 6.9e7 bank-conflict cycles) regardless of
// VGPR budget. This version uses ONLY named scalars:
//  - srcv: 16 named wave-uniform loads s0..s15 (uniform addr -> SMEM s_load)
//  - half-select u0..u7 via cndmask; tail-mask per element (edge k+2j+half)
//  - 8 named u2v gathers t0..t7: one dwordx2 fetches TWO 256-B rows
//    (lanes 0-31 -> even edge, lanes 32-63 -> odd edge; 8 B/lane)
//  - __shfl_xor(32) cross-half reduce; half-wave dwordx2 store (layout kept)
// ---------------------------------------------------------------------------
template<int SIN>
__global__ __launch_bounds__(256, 4) void propagate2(const unsigned* __restrict__ T0i,
                                                     unsigned* __restrict__ T0o,
                                                     const unsigned* __restrict__ T1i,
                                                     unsigned* __restrict__ T1o,
                                                     const int* __restrict__ ptrv,
                                                     const int* __restrict__ srcv,
                                                     const float* __restrict__ dinv) {
    int bid = blockIdx.x;
    int g = bid >= GPB;
    bid -= g * GPB;
    const unsigned* Tin = g ? T1i : T0i;
    unsigned* Tout      = g ? T1o : T0o;
    const int* pv   = ptrv + g * (N_NODES + 1);
    const int* sv   = srcv + (size_t)g * NE;
    const float* dp = dinv + g * N_NODES;
    int gid  = bid * 256 + threadIdx.x;
    int lane = threadIdx.x & 63;
    int half = lane >> 5;
    int l31  = lane & 31;
    int v    = __builtin_amdgcn_readfirstlane(gid >> 6);
    if (v >= N_NODES) return;
    float dv = dp[v];

    // self row in half 0; half 1 reads the zero dummy row (L1-hot)
    int uuS = half ? N_NODES : v;
    u2v sw = *(const u2v*)&Tin[(size_t)(unsigned)uuS * SIN + l31 * 2];
    float2 p0 = up2(sw.x), p1 = up2(sw.y);
    float a0 = p0.x, a1 = p0.y, a2 = p1.x, a3 = p1.y;

    int beg = pv[v], end = pv[v + 1];
    for (int k = beg; k < end; k += 16) {
        // 16 wave-uniform index loads (SMEM path; +16-int buffer slack
        // makes the unmasked tail read safe)
        int s0  = sv[k +  0], s1  = sv[k +  1], s2  = sv[k +  2], s3  = sv[k +  3];
        int s4  = sv[k +  4], s5  = sv[k +  5], s6  = sv[k +  6], s7  = sv[k +  7];
        int s8  = sv[k +  8], s9  = sv[k +  9], s10 = sv[k + 10], s11 = sv[k + 11];
        int s12 = sv[k + 12], s13 = sv[k + 13], s14 = sv[k + 14], s15 = sv[k + 15];
        // half-select: j-th gather serves edge k + 2j + half
        int u0 = half ? s1  : s0;
        int u1 = half ? s3  : s2;
        int u2 = half ? s5  : s4;
        int u3 = half ? s7  : s6;
        int u4 = half ? s9  : s8;
        int u5 = half ? s11 : s10;
        int u6 = half ? s13 : s12;
        int u7 = half ? s15 : s14;
        if (k + 16 > end) {                       // tail: mask to zero dummy row
            int eb = end - half;
            u0 = (k +  0 < eb) ? u0 : N_NODES;
            u1 = (k +  2 < eb) ? u1 : N_NODES;
            u2 = (k +  4 < eb) ? u2 : N_NODES;
            u3 = (k +  6 < eb) ? u3 : N_NODES;
            u4 = (k +  8 < eb) ? u4 : N_NODES;
            u5 = (k + 10 < eb) ? u5 : N_NODES;
            u6 = (k + 12 < eb) ? u6 : N_NODES;
            u7 = (k + 14 < eb) ? u7 : N_NODES;
        }
        __builtin_amdgcn_sched_barrier(0);
        u2v t0 = *(const u2v*)&Tin[(size_t)((unsigned)u0 * SIN) + l31 * 2];
        u2v t1 = *(const u2v*)&Tin[(size_t)((unsigned)u1 * SIN) + l31 * 2];
        u2v t2 = *(const u2v*)&Tin[(size_t)((unsigned)u2 * SIN) + l31 * 2];
        u2v t3 = *(const u2v*)&Tin[(size_t)((unsigned)u3 * SIN) + l31 * 2];
        u2v t4 = *(const u2v*)&Tin[(size_t)((unsigned)u4 * SIN) + l31 * 2];
        u2v t5 = *(const u2v*)&Tin[(size_t)((unsigned)u5 * SIN) + l31 * 2];
        u2v t6 = *(const u2v*)&Tin[(size_t)((unsigned)u6 * SIN) + l31 * 2];
        u2v t7 = *(const u2v*)&Tin[(size_t)((unsigned)u7 * SIN) + l31 * 2];
        __builtin_amdgcn_sched_barrier(0);
        float2 q;
        q = up2(t0.x); a0 += q.x; a1 += q.y;  q = up2(t0.y); a2 += q.x; a3 += q.y;
        q = up2(t1.x); a0 += q.x; a1 += q.y;  q = up2(t1.y); a2 += q.x; a3 += q.y;
        q = up2(t2.x); a0 += q.x; a1 += q.y;  q = up2(t2.y); a2 += q.x; a3 += q.y;
        q = up2(t3.x); a0 += q.x; a1 += q.y;  q = up2(t3.y); a2 += q.x; a3 += q.y;
        q = up2(t4.x); a0 += q.x; a1 += q.y;  q = up2(t4.y); a2 += q.x; a3 += q.y;
        q = up2(t5.x); a0 += q.x; a1 += q.y;  q = up2(t5.y); a2 += q.x; a3 += q.y;
        q = up2(t6.x); a0 += q.x; a1 += q.y;  q = up2(t6.y); a2 += q.x; a3 += q.y;
        q = up2(t7.x); a0 += q.x; a1 += q.y;  q = up2(t7.y); a2 += q.x; a3 += q.y;
    }
    // cross-half reduce: total over even-edge half + odd-edge half
    a0 += __shfl_xor(a0, 32);
    a1 += __shfl_xor(a1, 32);
    a2 += __shfl_xor(a2, 32);
    a3 += __shfl_xor(a3, 32);
    if (half == 0) {
        float s2 = dv * dv;
        u2v o;
        o.x = pk2(s2 * a0, s2 * a1);
        o.y = pk2(s2 * a2, s2 * a3);
        *(u2v*)&Tout[(size_t)v * 256 + l31 * 2] = o;
    }
}

// ---------------------------------------------------------------------------
// Branch-0 GEMM (round-2 proven structure: single 32KB LDS stage, 2 barriers
// per K-slice). H0[m][n] = fp16( sw0 * relu( acc[m][n]/dinv[m] + bs0[n] ) )
// ---------------------------------------------------------------------------
__global__ __launch_bounds__(256, 3) void gemmH0(
        const unsigned short* __restrict__ A0,
        const unsigned short* __restrict__ A,
        const unsigned short* __restrict__ Wt,
        const float* __restrict__ params,
        const float* __restrict__ dinv,
        unsigned short* __restrict__ H0) {
    __shared__ unsigned short Bl[DIM * DIM];   // 32 KB
    int t = threadIdx.x;
    int lane = t & 63, wv = t >> 6;
    int m0 = blockIdx.x * 128 + wv * 32;
    int l15 = lane & 15, q = lane >> 4;
    float sw0 = params[0];
    float bs[8];
#pragma unroll
    for (int nt = 0; nt < 8; ++nt) bs[nt] = params[2 + nt * 16 + l15];

    f4 acc[2][8];
#pragma unroll
    for (int mt = 0; mt < 2; ++mt)
#pragma unroll
        for (int nt = 0; nt < 8; ++nt) acc[mt][nt] = (f4)(0.f);

#pragma unroll
    for (int i = 0; i < 5; ++i) {
        const unsigned short* WtI = Wt + (size_t)i * DIM * DIM;
        const unsigned short* Ai = (i == 0) ? A0 : (A + (size_t)(i - 1) * DIM);
        const int rs = (i == 0) ? DIM : 512;
        h8 af[2][4];
#pragma unroll
        for (int mt = 0; mt < 2; ++mt)
#pragma unroll
            for (int kc = 0; kc < 4; ++kc)
                af[mt][kc] = *(const h8*)(Ai + (size_t)(m0 + mt * 16 + l15) * rs
                                             + (kc * 4 + q) * 8);
#pragma unroll
        for (int c = 0; c < 8; ++c) {
            int ci = c * 4 + wv;
            async_cp16(WtI + ci * 512 + lane * 8, &Bl[ci * 512]);
        }
        __syncthreads();
#pragma unroll
        for (int kc = 0; kc < 4; ++kc) {
            int c = kc * 4 + q;
#pragma unroll
            for (int nt = 0; nt < 8; ++nt) {
                h8 bf = *(const h8*)&Bl[(size_t)(c * 128 + nt * 16 + l15) * 8];
                acc[0][nt] = __builtin_amdgcn_mfma_f32_16x16x32_f16(af[0][kc], bf, acc[0][nt], 0, 0, 0);
                acc[1][nt] = __builtin_amdgcn_mfma_f32_16x16x32_f16(af[1][kc], bf, acc[1][nt], 0, 0, 0);
            }
        }
        __syncthreads();
    }
#pragma unroll
    for (int mt = 0; mt < 2; ++mt) {
        float rd[4];
#pragma unroll
        for (int r = 0; r < 4; ++r) {
            int row = m0 + mt * 16 + q * 4 + r;
            rd[r] = 1.0f / dinv[row < N_NODES ? row : (N_NODES - 1)];
        }
#pragma unroll
        for (int nt = 0; nt < 8; ++nt) {
#pragma unroll
            for (int r = 0; r < 4; ++r) {
                int row = m0 + mt * 16 + q * 4 + r;
                H0[(size_t)row * DIM + nt * 16 + l15] =
                    f2hbits(sw0 * fmaxf(rd[r] * acc[mt][nt][r] + bs[nt], 0.f));
            }
        }
    }
}

// ---------------------------------------------------------------------------
// Branch-1 GEMM + fusion + classifier (round-2 proven; Hl aliases staging).
// ---------------------------------------------------------------------------
__global__ __launch_bounds__(256, 2) void gemm_fused2(
        const unsigned short* __restrict__ A0,
        const unsigned short* __restrict__ A,
        const unsigned short* __restrict__ Wt,
        const unsigned short* __restrict__ H0,
        const float* __restrict__ params,
        const float* __restrict__ dinv,
        const unsigned short* __restrict__ clfWt,
        const float* __restrict__ clfB,
        float* __restrict__ out) {
    __shared__ unsigned short BlH[DIM * 132];   // 33.8 KB
    unsigned short* Bl = BlH;
    unsigned short* Hl = BlH;
    int t = threadIdx.x;
    int lane = t & 63, wv = t >> 6;
    int m0 = blockIdx.x * 128 + wv * 32;
    int l15 = lane & 15, q = lane >> 4;
    float sw1 = params[1];
    float bs[8];
#pragma unroll
    for (int nt = 0; nt < 8; ++nt) bs[nt] = params[130 + nt * 16 + l15];

    f4 acc[2][8];
#pragma unroll
    for (int mt = 0; mt < 2; ++mt)
#pragma unroll
        for (int nt = 0; nt < 8; ++nt) acc[mt][nt] = (f4)(0.f);

#pragma unroll
    for (int i = 0; i < 5; ++i) {
        const unsigned short* WtI = Wt + (size_t)i * DIM * DIM;
        const unsigned short* Ai = (i == 0) ? A0 : (A + (size_t)(i - 1) * DIM);
        const int rs = (i == 0) ? DIM : 512;
        h8 af[2][4];
#pragma unroll
        for (int mt = 0; mt < 2; ++mt)
#pragma unroll
            for (int kc = 0; kc < 4; ++kc)
                af[mt][kc] = *(const h8*)(Ai + (size_t)(m0 + mt * 16 + l15) * rs
                                             + (kc * 4 + q) * 8);
#pragma unroll
        for (int c = 0; c < 8; ++c) {
            int ci = c * 4 + wv;
            async_cp16(WtI + ci * 512 + lane * 8, &Bl[ci * 512]);
        }
        __syncthreads();
#pragma unroll
        for (int kc = 0; kc < 4; ++kc) {
            int c = kc * 4 + q;
#pragma unroll
            for (int nt = 0; nt < 8; ++nt) {
                h8 bf = *(const h8*)&Bl[(size_t)(c * 128 + nt * 16 + l15) * 8];
                acc[0][nt] = __builtin_amdgcn_mfma_f32_16x16x32_f16(af[0][kc], bf, acc[0][nt], 0, 0, 0);
                acc[1][nt] = __builtin_amdgcn_mfma_f32_16x16x32_f16(af[1][kc], bf, acc[1][nt], 0, 0, 0);
            }
        }
        __syncthreads();
    }

    // fuse with H0 (global read, 0 bank conflicts) into LDS Hl
#pragma unroll
    for (int mt = 0; mt < 2; ++mt) {
        float rd[4];
#pragma unroll
        for (int r = 0; r < 4; ++r) {
            int row = m0 + mt * 16 + q * 4 + r;
            rd[r] = 1.0f / dinv[row < N_NODES ? row : (N_NODES - 1)];
        }
#pragma unroll
        for (int nt = 0; nt < 8; ++nt) {
            int col = nt * 16 + l15;
#pragma unroll
            for (int r = 0; r < 4; ++r) {
                int lrow = wv * 32 + mt * 16 + q * 4 + r;
                int grow = m0 + mt * 16 + q * 4 + r;
                float h = sw1 * fmaxf(rd[r] * acc[mt][nt][r] + bs[nt], 0.f)
                        + h2f(H0[(size_t)grow * DIM + col]);
                Hl[lrow * 132 + col] = f2hbits(h);
            }
        }
    }
    __syncthreads();

    f4 o[2][4];
#pragma unroll
    for (int mt = 0; mt < 2; ++mt)
#pragma unroll
        for (int n2 = 0; n2 < 4; ++n2) o[mt][n2] = (f4)(0.f);
#pragma unroll
    for (int kc = 0; kc < 4; ++kc) {
        int c = kc * 4 + q;
        h8 ha[2];
#pragma unroll
        for (int mt = 0; mt < 2; ++mt)
            ha[mt] = *(const h8*)&Hl[(wv * 32 + mt * 16 + l15) * 132 + c * 8];
#pragma unroll
        for (int n2 = 0; n2 < 4; ++n2) {
            h8 bf = *(const h8*)&clfWt[(size_t)(n2 * 16 + l15) * DIM + c * 8];
            o[0][n2] = __builtin_amdgcn_mfma_f32_16x16x32_f16(ha[0], bf, o[0][n2], 0, 0, 0);
            o[1][n2] = __builtin_amdgcn_mfma_f32_16x16x32_f16(ha[1], bf, o[1][n2], 0, 0, 0);
        }
    }
#pragma unroll
    for (int mt = 0; mt < 2; ++mt)
#pragma unroll
        for (int n2 = 0; n2 < 4; ++n2) {
            int col = n2 * 16 + l15;
            float cbv = clfB[col];
#pragma unroll
            for (int r = 0; r < 4; ++r) {
                int row = m0 + mt * 16 + q * 4 + r;
                if (row < N_NODES) out[(size_t)row * ODIM + col] = o[mt][n2][r] + cbv;
            }
        }
}

// ---------------------------------------------------------------------------
extern "C" void kernel_launch(void* const* d_in, const int* in_sizes, int n_in,
                              void* d_out, int out_size, void* d_ws, size_t ws_size,
                              hipStream_t stream) {
    const float* x   = (const float*)d_in[0];
    const int*   ei  = (const int*)d_in[1];
    const int*   gi  = (const int*)d_in[2];
    const float* w_o = (const float*)d_in[3];
    const float* b_o = (const float*)d_in[4];
    const float* w_a = (const float*)d_in[5];
    const float* b_a = (const float*)d_in[6];
    const float* fw  = (const float*)d_in[7];
    const float* cw  = (const float*)d_in[8];
    const float* cb  = (const float*)d_in[9];
    float* out = (float*)d_out;

    auto align256 = [](size_t b) { return (b + 255) & ~(size_t)255; };
    const size_t szTbig = (size_t)NPAD * 256 * 4;            // 102.5 MB
    const size_t szS0   = (size_t)NPAD * 64 * 4;             // 25.6 MB
    const size_t szH0   = (size_t)NPAD * DIM * 2;            // 25.6 MB
    const size_t szWt   = ((size_t)2 * 5 * DIM * DIM + ODIM * DIM) * 2;
    const size_t szPar  = 258 * 4;
    const size_t szDinv = (size_t)2 * N_NODES * 4;
    const size_t szPairs= (size_t)2 * NE * 4;                // 12.8 MB
    const size_t szSrc  = ((size_t)2 * NE + 16) * 4;         // +16-int slack for tail reads
    const size_t szPtr  = (size_t)2 * (N_NODES + 1) * 4;
    const size_t szBh   = (size_t)2 * NB * 4;
    const size_t szBo   = (size_t)2 * (NB + 1) * 4;

    // merged layout: 2x Tbig, pairs aliased into Tbig_a (dead before 1st write)
    const size_t needBig = align256(szTbig) * 2 + align256(szS0) * 2 + align256(szH0)
                         + align256(szWt) + align256(szPar) + align256(szDinv)
                         + align256(szSrc) + align256(szPtr) + align256(szBh) * 2
                         + align256(szBo);
    const bool big = (ws_size >= needBig);

    char* p = (char*)d_ws;
    auto alloc = [&](size_t bytes) {
        void* r = (void*)p;
        p += (bytes + 255) & ~(size_t)255;
        return r;
    };
    unsigned* Tbig_o = (unsigned*)alloc(szTbig);
    unsigned* Tbig_a = big ? (unsigned*)alloc(szTbig) : Tbig_o;
    unsigned* pairs  = big ? Tbig_a : (unsigned*)alloc(szPairs);
    unsigned* S0o  = (unsigned*)alloc(szS0);
    unsigned* S0a  = (unsigned*)alloc(szS0);
    unsigned short* H0 = (unsigned short*)alloc(szH0);
    unsigned short* Wt = (unsigned short*)alloc(szWt);
    float* params = (float*)alloc(szPar);
    float* dinv  = (float*)alloc(szDinv);
    int* csr_src = (int*)alloc(szSrc);
    int* csr_ptr = (int*)alloc(szPtr);
    int* bhist   = (int*)alloc(szBh);
    int* boff    = (int*)alloc(szBo);
    int* bcursor = (int*)alloc(szBh);

    const int gX  = (NPAD * 64 + 255) / 256;        // 25024
    const int gW  = (2 * 5 * DIM * DIM + ODIM * DIM + 255) / 256;
    const int gM  = NPAD / 128;                     // 782

    // wcast also zeroes bhist (first dispatch on the stream)
    wcast<<<gW, 256, 0, stream>>>(w_o, w_a, cw, b_o, b_a, fw, Wt, params, bhist);

    // ---- CSR build for BOTH graphs ----
    hist_edges<<<2 * 782, 256, 0, stream>>>(ei, gi, bhist);
    wave_scan<<<1, 128, 0, stream>>>(bhist, boff, bcursor, NB);
    part_edges<<<2 * PB_BLKS, 1024, 0, stream>>>(ei, gi, bcursor, pairs);
    bucket_csr<<<2 * NB, 256, 0, stream>>>(pairs, boff, csr_ptr, dinv, csr_src);

    // ---- S0 slices + Tbig pad-row zeroing ----
    s0cast<<<gX, 256, 0, stream>>>(x, dinv, S0o, S0a, Tbig_o, Tbig_a);

    if (big) {
        // ---- both branches propagate in one dispatch per order ----
        propagate2<64><<<2 * GPB, 256, 0, stream>>>(S0o, Tbig_o, S0a, Tbig_a,
                                                    csr_ptr, csr_src, dinv);
        propagate2<256><<<2 * GPB, 256, 0, stream>>>(Tbig_o, Tbig_o + 64,
                                                     Tbig_a, Tbig_a + 64,
                                                     csr_ptr, csr_src, dinv);
        propagate2<256><<<2 * GPB, 256, 0, stream>>>(Tbig_o + 64, Tbig_o + 128,
                                                     Tbig_a + 64, Tbig_a + 128,
                                                     csr_ptr, csr_src, dinv);
        propagate2<256><<<2 * GPB, 256, 0, stream>>>(Tbig_o + 128, Tbig_o + 192,
                                                     Tbig_a + 128, Tbig_a + 192,
                                                     csr_ptr, csr_src, dinv);
        gemmH0<<<gM, 256, 0, stream>>>((const unsigned short*)S0o,
                                       (const unsigned short*)Tbig_o,
                                       Wt, params, dinv, H0);
        gemm_fused2<<<gM, 256, 0, stream>>>((const unsigned short*)S0a,
                                            (const unsigned short*)Tbig_a,
                                            Wt + (size_t)5 * DIM * DIM,
                                            H0, params, dinv + N_NODES,
                                            Wt + (size_t)2 * 5 * DIM * DIM, cb, out);
    } else {
        // ---- fallback: sequential branches sharing one Tbig ----
        propagate2<64><<<GPB, 256, 0, stream>>>(S0o, Tbig_o, S0o, Tbig_o,
                                                csr_ptr, csr_src, dinv);
        propagate2<256><<<GPB, 256, 0, stream>>>(Tbig_o, Tbig_o + 64, Tbig_o, Tbig_o + 64,
                                                 csr_ptr, csr_src, dinv);
        propagate2<256><<<GPB, 256, 0, stream>>>(Tbig_o + 64, Tbig_o + 128,
                                                 Tbig_o + 64, Tbig_o + 128,
                                                 csr_ptr, csr_src, dinv);
        propagate2<256><<<GPB, 256, 0, stream>>>(Tbig_o + 128, Tbig_o + 192,
                                                 Tbig_o + 128, Tbig_o + 192,
                                                 csr_ptr, csr_src, dinv);
        gemmH0<<<gM, 256, 0, stream>>>((const unsigned short*)S0o,
                                       (const unsigned short*)Tbig_o,
                                       Wt, params, dinv, H0);
        const int* pv = csr_ptr + (N_NODES + 1);
        const int* sv = csr_src + (size_t)NE;
        const float* dv = dinv + (size_t)N_NODES;
        propagate2<64><<<GPB, 256, 0, stream>>>(S0a, Tbig_o, S0a, Tbig_o, pv, sv, dv);
        propagate2<256><<<GPB, 256, 0, stream>>>(Tbig_o, Tbig_o + 64, Tbig_o, Tbig_o + 64,
                                                 pv, sv, dv);
        propagate2<256><<<GPB, 256, 0, stream>>>(Tbig_o + 64, Tbig_o + 128,
                                                 Tbig_o + 64, Tbig_o + 128, pv, sv, dv);
        propagate2<256><<<GPB, 256, 0, stream>>>(Tbig_o + 128, Tbig_o + 192,
                                                 Tbig_o + 128, Tbig_o + 192, pv, sv, dv);
        gemm_fused2<<<gM, 256, 0, stream>>>((const unsigned short*)S0a,
                                            (const unsigned short*)Tbig_o,
                                            Wt + (size_t)5 * DIM * DIM,
                                            H0, params, dinv + N_NODES,
                                            Wt + (size_t)2 * 5 * DIM * DIM, cb, out);
    }
}